// Round 1
// baseline (512.628 us; speedup 1.0000x reference)
//
#include <hip/hip_runtime.h>

#define M_TOK 2048
#define KDIM 2048
#define NDIM 1408
#define NEXP 8
#define RROWS (M_TOK * 2)
#define CAP 1024

typedef __attribute__((ext_vector_type(8))) short short8;
typedef __attribute__((ext_vector_type(4))) float f32x4;

__device__ __forceinline__ unsigned short bf16rn(float f) {
    unsigned int u = __builtin_bit_cast(unsigned int, f);
    u += 0x7FFFu + ((u >> 16) & 1u);
    return (unsigned short)(u >> 16);
}
__device__ __forceinline__ unsigned int pk2(float a, float b) {
    return (unsigned int)bf16rn(a) | ((unsigned int)bf16rn(b) << 16);
}

// ---------------- routing + dispatch (fp32 -> bf16 row copy) ----------------
__global__ void k_route(const float* __restrict__ h, const int* __restrict__ idx,
                        const float* __restrict__ gate, int* __restrict__ cnt,
                        int* __restrict__ tok_of, float* __restrict__ gate_of,
                        unsigned short* __restrict__ bufA) {
    int r = blockIdx.x;
    __shared__ int s_ep;
    if (threadIdx.x == 0) {
        int e = idx[r];
        int p = atomicAdd(&cnt[e], 1);
        tok_of[e * CAP + p] = r >> 1;
        gate_of[e * CAP + p] = gate[r];
        s_ep = e * CAP + p;
    }
    __syncthreads();
    int ep = s_ep;
    const float4* src = (const float4*)(h + (size_t)(r >> 1) * KDIM) + threadIdx.x * 2;
    float4 a = src[0], b = src[1];
    uint4 o;
    o.x = pk2(a.x, a.y); o.y = pk2(a.z, a.w);
    o.z = pk2(b.x, b.y); o.w = pk2(b.z, b.w);
    *((uint4*)(bufA + (size_t)ep * KDIM) + threadIdx.x) = o;
}

// ---------------- GEMM1: g,u = A @ W^T ; h = silu(min(g,10)) * clip(u) ------
__global__ __launch_bounds__(256, 2)
void k_gemm1(const unsigned short* __restrict__ bufA,
             const float* __restrict__ gw, const float* __restrict__ uw,
             const int* __restrict__ cnt, unsigned short* __restrict__ hbuf) {
    const int e = blockIdx.z;
    const int m0 = blockIdx.y * 128;
    if (m0 >= cnt[e]) return;
    const int n0 = blockIdx.x * 128;

    const unsigned short* A = bufA + (size_t)e * CAP * KDIM;
    const float* Bg = gw + (size_t)e * NDIM * KDIM;
    const float* Bu = uw + (size_t)e * NDIM * KDIM;

    __shared__ unsigned short sA[128 * 40];
    __shared__ unsigned short sG[128 * 40];
    __shared__ unsigned short sU[128 * 40];

    const int tid = threadIdx.x;
    const int lane = tid & 63;
    const int wave = tid >> 6;
    const int wm = (wave >> 1) * 64, wn = (wave & 1) * 64;
    const int q = lane >> 4, l15 = lane & 15;

    f32x4 accG[4][4] = {};
    f32x4 accU[4][4] = {};

    for (int k0 = 0; k0 < KDIM; k0 += 32) {
        __syncthreads();
#pragma unroll
        for (int g = 0; g < 2; g++) {
            int gg = tid + g * 256;
            int row = gg >> 2, c8 = (gg & 3) * 8;
            *(uint4*)&sA[row * 40 + c8] =
                *(const uint4*)(A + (size_t)(m0 + row) * KDIM + k0 + c8);
        }
#pragma unroll
        for (int g = 0; g < 2; g++) {
            int gg = tid + g * 256;
            int row = gg >> 2, c8 = (gg & 3) * 8;
            const float4* pg = (const float4*)(Bg + (size_t)(n0 + row) * KDIM + k0 + c8);
            float4 a = pg[0], b = pg[1];
            uint4 o;
            o.x = pk2(a.x, a.y); o.y = pk2(a.z, a.w);
            o.z = pk2(b.x, b.y); o.w = pk2(b.z, b.w);
            *(uint4*)&sG[row * 40 + c8] = o;
            const float4* pu = (const float4*)(Bu + (size_t)(n0 + row) * KDIM + k0 + c8);
            a = pu[0]; b = pu[1];
            o.x = pk2(a.x, a.y); o.y = pk2(a.z, a.w);
            o.z = pk2(b.x, b.y); o.w = pk2(b.z, b.w);
            *(uint4*)&sU[row * 40 + c8] = o;
        }
        __syncthreads();

        short8 af[4], gf[4], uf[4];
#pragma unroll
        for (int i = 0; i < 4; i++) {
            af[i] = *(const short8*)&sA[(wm + i * 16 + l15) * 40 + q * 8];
            gf[i] = *(const short8*)&sG[(wn + i * 16 + l15) * 40 + q * 8];
            uf[i] = *(const short8*)&sU[(wn + i * 16 + l15) * 40 + q * 8];
        }
#pragma unroll
        for (int i = 0; i < 4; i++)
#pragma unroll
            for (int j = 0; j < 4; j++) {
                accG[i][j] = __builtin_amdgcn_mfma_f32_16x16x32_bf16(af[i], gf[j], accG[i][j], 0, 0, 0);
                accU[i][j] = __builtin_amdgcn_mfma_f32_16x16x32_bf16(af[i], uf[j], accU[i][j], 0, 0, 0);
            }
    }

    unsigned short* H = hbuf + (size_t)e * CAP * NDIM;
#pragma unroll
    for (int i = 0; i < 4; i++)
#pragma unroll
        for (int j = 0; j < 4; j++) {
            int col = n0 + wn + j * 16 + l15;
#pragma unroll
            for (int rg = 0; rg < 4; rg++) {
                int row = m0 + wm + i * 16 + q * 4 + rg;
                float g = accG[i][j][rg];
                float u = accU[i][j][rg];
                g = fminf(g, 10.f);
                u = fminf(fmaxf(u, -10.f), 10.f);
                float hv = g / (1.f + __expf(-g)) * u;
                H[(size_t)row * NDIM + col] = bf16rn(hv);
            }
        }
}

// ---------------- GEMM2: d = h @ dw^T ; out[tok] += gate * d ----------------
__global__ __launch_bounds__(256, 2)
void k_gemm2(const unsigned short* __restrict__ hbuf,
             const float* __restrict__ dw, const int* __restrict__ cnt,
             const int* __restrict__ tok_of, const float* __restrict__ gate_of,
             float* __restrict__ out) {
    const int e = blockIdx.z;
    const int cnt_e = cnt[e];
    const int m0 = blockIdx.y * 128;
    if (m0 >= cnt_e) return;
    const int n0 = blockIdx.x * 128;  // over KDIM (output columns)

    const unsigned short* A = hbuf + (size_t)e * CAP * NDIM;
    const float* B = dw + (size_t)e * KDIM * NDIM;

    __shared__ unsigned short sA[128 * 40];
    __shared__ unsigned short sB[128 * 40];

    const int tid = threadIdx.x;
    const int lane = tid & 63;
    const int wave = tid >> 6;
    const int wm = (wave >> 1) * 64, wn = (wave & 1) * 64;
    const int q = lane >> 4, l15 = lane & 15;

    f32x4 acc[4][4] = {};

    for (int k0 = 0; k0 < NDIM; k0 += 32) {
        __syncthreads();
#pragma unroll
        for (int g = 0; g < 2; g++) {
            int gg = tid + g * 256;
            int row = gg >> 2, c8 = (gg & 3) * 8;
            *(uint4*)&sA[row * 40 + c8] =
                *(const uint4*)(A + (size_t)(m0 + row) * NDIM + k0 + c8);
        }
#pragma unroll
        for (int g = 0; g < 2; g++) {
            int gg = tid + g * 256;
            int row = gg >> 2, c8 = (gg & 3) * 8;
            const float4* pb = (const float4*)(B + (size_t)(n0 + row) * NDIM + k0 + c8);
            float4 a = pb[0], b = pb[1];
            uint4 o;
            o.x = pk2(a.x, a.y); o.y = pk2(a.z, a.w);
            o.z = pk2(b.x, b.y); o.w = pk2(b.z, b.w);
            *(uint4*)&sB[row * 40 + c8] = o;
        }
        __syncthreads();

        short8 af[4], bfr[4];
#pragma unroll
        for (int i = 0; i < 4; i++) {
            af[i] = *(const short8*)&sA[(wm + i * 16 + l15) * 40 + q * 8];
            bfr[i] = *(const short8*)&sB[(wn + i * 16 + l15) * 40 + q * 8];
        }
#pragma unroll
        for (int i = 0; i < 4; i++)
#pragma unroll
            for (int j = 0; j < 4; j++)
                acc[i][j] = __builtin_amdgcn_mfma_f32_16x16x32_bf16(af[i], bfr[j], acc[i][j], 0, 0, 0);
    }

#pragma unroll
    for (int i = 0; i < 4; i++) {
#pragma unroll
        for (int rg = 0; rg < 4; rg++) {
            int row = m0 + wm + i * 16 + q * 4 + rg;
            if (row < cnt_e) {
                int tok = tok_of[e * CAP + row];
                float gt = gate_of[e * CAP + row];
                float* orow = out + (size_t)tok * KDIM + n0 + wn + l15;
#pragma unroll
                for (int j = 0; j < 4; j++)
                    atomicAdd(orow + j * 16, acc[i][j][rg] * gt);
            }
        }
    }
}

extern "C" void kernel_launch(void* const* d_in, const int* in_sizes, int n_in,
                              void* d_out, int out_size, void* d_ws, size_t ws_size,
                              hipStream_t stream) {
    const float* flat_h = (const float*)d_in[0];
    const int* flat_idx = (const int*)d_in[1];
    const float* flat_gate = (const float*)d_in[2];
    const float* gw = (const float*)d_in[3];
    const float* uw = (const float*)d_in[4];
    const float* dwn = (const float*)d_in[5];
    float* out = (float*)d_out;

    char* w = (char*)d_ws;
    int* cnt = (int*)w;                                  // 32 B (256 reserved)
    int* tok_of = (int*)(w + 256);                       // 32 KB
    float* gate_of = (float*)(w + 256 + NEXP * CAP * 4); // 32 KB
    unsigned short* bufA = (unsigned short*)(w + 256 + 2 * NEXP * CAP * 4);
    unsigned short* hbuf = (unsigned short*)(w + 256 + 2 * NEXP * CAP * 4 +
                                             (size_t)NEXP * CAP * KDIM * 2);

    hipMemsetAsync(cnt, 0, 256, stream);
    hipMemsetAsync(out, 0, (size_t)M_TOK * KDIM * 4, stream);

    k_route<<<RROWS, 256, 0, stream>>>(flat_h, flat_idx, flat_gate, cnt, tok_of, gate_of, bufA);
    k_gemm1<<<dim3(NDIM / 128, CAP / 128, NEXP), 256, 0, stream>>>(bufA, gw, uw, cnt, hbuf);
    k_gemm2<<<dim3(KDIM / 128, CAP / 128, NEXP), 256, 0, stream>>>(hbuf, dwn, cnt, tok_of, gate_of, out);
}